// Round 11
// baseline (77.761 us; speedup 1.0000x reference)
//
#include <hip/hip_runtime.h>
#include <stdint.h>

// Problem dims (fixed by reference): E=16, B=8, S=2048, D=2048
#define N_TOK   16384          // B*S
#define D_MODEL 2048
#define N_EXP   16
#define CAP     1024           // N_TOK / N_EXP

#define BLK_TOK 4              // token rows per combine block
#define THREADS 256
#define STEPS   8              // float4 groups per thread (4 rows x 512 / 256)
#define NBLK    (N_TOK / BLK_TOK)   // 4096 blocks = 2.0x chip residency

// keep  <=>  u < 0.9f  <=>  bits < 7549747<<9  (0.9f == 7549747*2^-23 exactly)
#define KEEP_THR_SH 0xE6666600u

// native 4-float vector for nontemporal builtins (HIP_vector_type is a class)
typedef float nfloat4 __attribute__((ext_vector_type(4)));

__device__ __forceinline__ float4 ntload4(const float4* p) {
    nfloat4 v = __builtin_nontemporal_load((const nfloat4*)p);
    return make_float4(v.x, v.y, v.z, v.w);
}

// ---------------------------------------------------------------------------
// rotl forced to a single v_alignbit_b32: rotl(x,r) == {x,x} >> (32-r).
// ---------------------------------------------------------------------------
template <int R>
__device__ __forceinline__ uint32_t rotl(uint32_t x) {
    uint32_t d;
    asm("v_alignbit_b32 %0, %1, %1, %2" : "=v"(d) : "v"(x), "n"(32 - R));
    return d;
}

// ---------------------------------------------------------------------------
// Threefry-2x32, 20 rounds, key = (0, 42) == jax.random.key(42).
// Partitionable path: counter = (0, i); 32-bit draw = XOR-fold x0 ^ x1.
// ---------------------------------------------------------------------------
__device__ __forceinline__ uint32_t tf_bits(uint32_t i) {
    const uint32_t k0 = 0u;
    const uint32_t k1 = 42u;
    const uint32_t k2 = 0x1BD11BDAu ^ 0u ^ 42u;
    uint32_t x0 = 0u + k0;        // counter hi = 0
    uint32_t x1 = i + k1;         // counter lo = i
#define TF_R(r) { x0 += x1; x1 = rotl<r>(x1) ^ x0; }
    TF_R(13) TF_R(15) TF_R(26) TF_R(6)
    x0 += k1; x1 += k2 + 1u;
    TF_R(17) TF_R(29) TF_R(16) TF_R(24)
    x0 += k2; x1 += k0 + 2u;
    TF_R(13) TF_R(15) TF_R(26) TF_R(6)
    x0 += k0; x1 += k1 + 3u;
    TF_R(17) TF_R(29) TF_R(16) TF_R(24)
    x0 += k1; x1 += k2 + 4u;
    TF_R(13) TF_R(15) TF_R(26) TF_R(6)
    x0 += k2; x1 += k0 + 5u;
#undef TF_R
    return x0 ^ x1;               // XOR-fold (partitionable sub-64 narrowing)
}

// ---------------------------------------------------------------------------
// Kernel 1: within-expert rank, two-level scan, single pass over routes.
// 16 blocks (one per expert) x 1024 threads (16 waves).
// srcrow[t] = routes[t]*CAP + rank(t).
// ---------------------------------------------------------------------------
__global__ __launch_bounds__(1024) void rank_kernel(const int* __restrict__ routes,
                                                    int* __restrict__ srcrow) {
    const int e    = blockIdx.x;
    const int tid  = threadIdx.x;       // 0..1023
    const int wave = tid >> 6;          // 0..15
    const int lane = tid & 63;
    __shared__ int wave_tot[16];

    const int4* r4 = (const int4*)routes;
    int4 rv[4];
    int  mycnt = 0;
    #pragma unroll
    for (int q = 0; q < 4; ++q) {
        rv[q] = r4[(wave << 8) + (lane << 2) + q];   // 16 consecutive tokens/lane
        mycnt += (rv[q].x == e) + (rv[q].y == e) + (rv[q].z == e) + (rv[q].w == e);
    }

    // inclusive wave scan of mycnt over lanes
    int pre = mycnt;
    #pragma unroll
    for (int d = 1; d < 64; d <<= 1) {
        int up = __shfl_up(pre, d);
        if (lane >= d) pre += up;
    }
    if (lane == 63) wave_tot[wave] = pre;
    __syncthreads();

    int wbase = 0;
    #pragma unroll
    for (int w = 0; w < 16; ++w) wbase += (w < wave) ? wave_tot[w] : 0;

    int p = e * CAP + wbase + (pre - mycnt);   // rank of lane's first match
    #pragma unroll
    for (int q = 0; q < 4; ++q) {
        const int tok = (((wave << 8) + (lane << 2) + q) << 2);
        if (rv[q].x == e) srcrow[tok + 0] = p++;
        if (rv[q].y == e) srcrow[tok + 1] = p++;
        if (rv[q].z == e) srcrow[tok + 2] = p++;
        if (rv[q].w == e) srcrow[tok + 3] = p++;
    }
}

// ---------------------------------------------------------------------------
// Kernel 2: combine + dropout + residual.
// 4096 blocks (2x residency for tail backfill), 8 steps/thread, 2-deep
// rolling prefetch in NAMED registers (no arrays -> no spill), pinned with
// sched_barrier. NT store: output never re-read.
// ---------------------------------------------------------------------------
__global__ __launch_bounds__(THREADS, 8) void combine_kernel(
        const float4* __restrict__ hidden,
        const float4* __restrict__ eo4,
        const int*    __restrict__ srcrow,
        const float*  __restrict__ rpm,
        float4*       __restrict__ out) {
    const int b     = blockIdx.x;
    const int tid   = threadIdx.x;                 // 0..255
    const int t0    = b * BLK_TOK;
    const int gbase = b * (BLK_TOK * 512);         // first float4 of block

    // Block-uniform per-row scalars (scalarize to SGPRs), paid once per block
    int   r[BLK_TOK];
    float sc[BLK_TOK];
    #pragma unroll
    for (int q = 0; q < BLK_TOK; ++q) {
        r[q]  = srcrow[t0 + q];
        sc[q] = rpm[t0 + q] * (1.0f / 0.9f);
    }

    // 2-deep rolling pipeline, named registers only.
    float4 h0 = ntload4(&hidden[gbase + tid]);
    float4 e0 = eo4[(r[0] << 9) + tid];
    float4 h1 = ntload4(&hidden[gbase + THREADS + tid]);
    float4 e1 = eo4[(r[0] << 9) + THREADS + tid];   // step1 token = 0 (2 steps/row)

    #pragma unroll
    for (int k = 0; k < STEPS; ++k) {
        float4 h2, e2;
        if (k + 2 < STEPS) {
            const int idx = (k + 2) * THREADS + tid;       // within-block f4 idx
            h2 = ntload4(&hidden[gbase + idx]);
            e2 = eo4[(r[(k + 2) >> 1] << 9) + (idx & 511)];
        }
        // pin: prefetch loads may not sink below; threefry may not hoist above
        __builtin_amdgcn_sched_barrier(0);

        const uint32_t j = (uint32_t)(gbase + k * THREADS + tid) << 2;
        const uint32_t b0 = tf_bits(j + 0);
        const uint32_t b1 = tf_bits(j + 1);
        const uint32_t b2 = tf_bits(j + 2);
        const uint32_t b3 = tf_bits(j + 3);

        const float s  = sc[k >> 1];
        const float m0 = (b0 < KEEP_THR_SH) ? s : 0.0f;
        const float m1 = (b1 < KEEP_THR_SH) ? s : 0.0f;
        const float m2 = (b2 < KEEP_THR_SH) ? s : 0.0f;
        const float m3 = (b3 < KEEP_THR_SH) ? s : 0.0f;

        nfloat4 o;
        o.x = fmaf(m0, e0.x, h0.x);
        o.y = fmaf(m1, e0.y, h0.y);
        o.z = fmaf(m2, e0.z, h0.z);
        o.w = fmaf(m3, e0.w, h0.w);
        __builtin_nontemporal_store(o, (nfloat4*)&out[gbase + k * THREADS + tid]);

        // rotate pipeline (full unroll -> pure register renaming, no copies)
        h0 = h1; e0 = e1;
        if (k + 2 < STEPS) { h1 = h2; e1 = e2; }
    }
}

// ---------------------------------------------------------------------------
extern "C" void kernel_launch(void* const* d_in, const int* in_sizes, int n_in,
                              void* d_out, int out_size, void* d_ws, size_t ws_size,
                              hipStream_t stream) {
    const float* hidden = (const float*)d_in[0];   // [B,S,D] f32
    const float* eo     = (const float*)d_in[1];   // [E,CAP,D] f32
    const int*   routes = (const int*)d_in[2];     // [N] i32
    const float* rpm    = (const float*)d_in[3];   // [N] f32

    int* srcrow = (int*)d_ws;                      // N_TOK ints = 64 KB scratch

    rank_kernel<<<N_EXP, 1024, 0, stream>>>(routes, srcrow);
    combine_kernel<<<NBLK, THREADS, 0, stream>>>(
        (const float4*)hidden, (const float4*)eo, srcrow, rpm, (float4*)d_out);
}

// Round 12
// 76.092 us; speedup vs baseline: 1.0219x; 1.0219x over previous
//
#include <hip/hip_runtime.h>
#include <stdint.h>

// Problem dims (fixed by reference): E=16, B=8, S=2048, D=2048
#define N_TOK   16384          // B*S
#define D_MODEL 2048
#define N_EXP   16
#define CAP     1024           // N_TOK / N_EXP

#define BLK_TOK 8              // token rows per combine block (R9 best)
#define THREADS 256
#define STEPS   16             // float4 groups per thread
#define NBLK    (N_TOK / BLK_TOK)   // 2048 blocks = 8192 waves = 32/CU exactly

// keep  <=>  u < 0.9f  <=>  bits < 7549747<<9  (0.9f == 7549747*2^-23 exactly)
#define KEEP_THR_SH 0xE6666600u

// native 4-float vector for nontemporal builtins (HIP_vector_type is a class)
typedef float nfloat4 __attribute__((ext_vector_type(4)));

__device__ __forceinline__ float4 ntload4(const float4* p) {
    nfloat4 v = __builtin_nontemporal_load((const nfloat4*)p);
    return make_float4(v.x, v.y, v.z, v.w);
}

// ---------------------------------------------------------------------------
// rotl forced to a single v_alignbit_b32: rotl(x,r) == {x,x} >> (32-r).
// ---------------------------------------------------------------------------
template <int R>
__device__ __forceinline__ uint32_t rotl(uint32_t x) {
    uint32_t d;
    asm("v_alignbit_b32 %0, %1, %1, %2" : "=v"(d) : "v"(x), "n"(32 - R));
    return d;
}

// ---------------------------------------------------------------------------
// Threefry-2x32, 20 rounds, key = (0, 42) == jax.random.key(42).
// Partitionable path: counter = (0, i); 32-bit draw = XOR-fold x0 ^ x1.
// Key-injection x0-adds are fused into the next round's x0 += x1 as
// x0 = x0 + k + x1' (v_add3_u32): saves 4 adds/element vs the naive form.
// ---------------------------------------------------------------------------
__device__ __forceinline__ uint32_t tf_bits(uint32_t i) {
    const uint32_t k1 = 42u;
    const uint32_t k2 = 0x1BD11BDAu ^ 42u;   // k0 = 0
    uint32_t x0 = 0u;                        // counter hi = 0, k0 = 0
    uint32_t x1 = i + k1;                    // counter lo = i

#define TF_ROT(r) { x0 += x1; x1 = rotl<r>(x1) ^ x0; }
    // rounds 1-4
    TF_ROT(13) TF_ROT(15) TF_ROT(26) TF_ROT(6)
    // inject (k1, k2+1) fused into round 5's add: x0 = x0 + k1 + x1'
    x1 += k2 + 1u; x0 += k1 + x1; x1 = rotl<17>(x1) ^ x0;
    TF_ROT(29) TF_ROT(16) TF_ROT(24)
    // inject (k2, k0+2)=(k2,2) fused into round 9's add
    x1 += 2u;      x0 += k2 + x1; x1 = rotl<13>(x1) ^ x0;
    TF_ROT(15) TF_ROT(26) TF_ROT(6)
    // inject (k0, k1+3)=(0,45) fused into round 13's add
    x1 += k1 + 3u; x0 += x1;      x1 = rotl<17>(x1) ^ x0;
    TF_ROT(29) TF_ROT(16) TF_ROT(24)
    // inject (k1, k2+4) fused into round 17's add
    x1 += k2 + 4u; x0 += k1 + x1; x1 = rotl<13>(x1) ^ x0;
    TF_ROT(15) TF_ROT(26) TF_ROT(6)
#undef TF_ROT
    // final injection + fold
    return (x0 + k2) ^ (x1 + 5u);
}

// ---------------------------------------------------------------------------
// Kernel 1: within-expert rank, two-level scan, single pass over routes.
// 16 blocks (one per expert) x 1024 threads (16 waves).
// srcrow[t] = routes[t]*CAP + rank(t).
// ---------------------------------------------------------------------------
__global__ __launch_bounds__(1024) void rank_kernel(const int* __restrict__ routes,
                                                    int* __restrict__ srcrow) {
    const int e    = blockIdx.x;
    const int tid  = threadIdx.x;       // 0..1023
    const int wave = tid >> 6;          // 0..15
    const int lane = tid & 63;
    __shared__ int wave_tot[16];

    const int4* r4 = (const int4*)routes;
    int4 rv[4];
    int  mycnt = 0;
    #pragma unroll
    for (int q = 0; q < 4; ++q) {
        rv[q] = r4[(wave << 8) + (lane << 2) + q];   // 16 consecutive tokens/lane
        mycnt += (rv[q].x == e) + (rv[q].y == e) + (rv[q].z == e) + (rv[q].w == e);
    }

    // inclusive wave scan of mycnt over lanes
    int pre = mycnt;
    #pragma unroll
    for (int d = 1; d < 64; d <<= 1) {
        int up = __shfl_up(pre, d);
        if (lane >= d) pre += up;
    }
    if (lane == 63) wave_tot[wave] = pre;
    __syncthreads();

    int wbase = 0;
    #pragma unroll
    for (int w = 0; w < 16; ++w) wbase += (w < wave) ? wave_tot[w] : 0;

    int p = e * CAP + wbase + (pre - mycnt);   // rank of lane's first match
    #pragma unroll
    for (int q = 0; q < 4; ++q) {
        const int tok = (((wave << 8) + (lane << 2) + q) << 2);
        if (rv[q].x == e) srcrow[tok + 0] = p++;
        if (rv[q].y == e) srcrow[tok + 1] = p++;
        if (rv[q].z == e) srcrow[tok + 2] = p++;
        if (rv[q].w == e) srcrow[tok + 3] = p++;
    }
}

// ---------------------------------------------------------------------------
// Kernel 2: combine + dropout + residual. R9 geometry (8 rows/block, 16
// steps), R11 2-deep rolling prefetch in NAMED registers, sched_barrier
// pins, NT load on streamed hidden, NT store on never-re-read out.
// ---------------------------------------------------------------------------
__global__ __launch_bounds__(THREADS, 8) void combine_kernel(
        const float4* __restrict__ hidden,
        const float4* __restrict__ eo4,
        const int*    __restrict__ srcrow,
        const float*  __restrict__ rpm,
        float4*       __restrict__ out) {
    const int b     = blockIdx.x;
    const int tid   = threadIdx.x;                 // 0..255
    const int t0    = b * BLK_TOK;
    const int gbase = b * (BLK_TOK * 512);         // first float4 of block

    // Block-uniform per-row scalars (scalarize to SGPRs), paid once per block
    int   r[BLK_TOK];
    float sc[BLK_TOK];
    #pragma unroll
    for (int q = 0; q < BLK_TOK; ++q) {
        r[q]  = srcrow[t0 + q];
        sc[q] = rpm[t0 + q] * (1.0f / 0.9f);
    }

    // 2-deep rolling pipeline, named registers only.
    float4 h0 = ntload4(&hidden[gbase + tid]);
    float4 e0 = eo4[(r[0] << 9) + tid];
    float4 h1 = ntload4(&hidden[gbase + THREADS + tid]);
    float4 e1 = eo4[(r[0] << 9) + THREADS + tid];   // step1 token = row 0

    #pragma unroll
    for (int k = 0; k < STEPS; ++k) {
        float4 h2, e2;
        if (k + 2 < STEPS) {
            const int idx = (k + 2) * THREADS + tid;       // within-block f4 idx
            h2 = ntload4(&hidden[gbase + idx]);
            e2 = eo4[(r[(k + 2) >> 1] << 9) + (idx & 511)];
        }
        // pin: prefetch loads may not sink below; threefry may not hoist above
        __builtin_amdgcn_sched_barrier(0);

        const uint32_t j = (uint32_t)(gbase + k * THREADS + tid) << 2;
        const uint32_t b0 = tf_bits(j + 0);
        const uint32_t b1 = tf_bits(j + 1);
        const uint32_t b2 = tf_bits(j + 2);
        const uint32_t b3 = tf_bits(j + 3);

        const float s  = sc[k >> 1];
        const float m0 = (b0 < KEEP_THR_SH) ? s : 0.0f;
        const float m1 = (b1 < KEEP_THR_SH) ? s : 0.0f;
        const float m2 = (b2 < KEEP_THR_SH) ? s : 0.0f;
        const float m3 = (b3 < KEEP_THR_SH) ? s : 0.0f;

        nfloat4 o;
        o.x = fmaf(m0, e0.x, h0.x);
        o.y = fmaf(m1, e0.y, h0.y);
        o.z = fmaf(m2, e0.z, h0.z);
        o.w = fmaf(m3, e0.w, h0.w);
        __builtin_nontemporal_store(o, (nfloat4*)&out[gbase + k * THREADS + tid]);

        // rotate pipeline (full unroll -> pure register renaming, no copies)
        h0 = h1; e0 = e1;
        if (k + 2 < STEPS) { h1 = h2; e1 = e2; }
    }
}

// ---------------------------------------------------------------------------
extern "C" void kernel_launch(void* const* d_in, const int* in_sizes, int n_in,
                              void* d_out, int out_size, void* d_ws, size_t ws_size,
                              hipStream_t stream) {
    const float* hidden = (const float*)d_in[0];   // [B,S,D] f32
    const float* eo     = (const float*)d_in[1];   // [E,CAP,D] f32
    const int*   routes = (const int*)d_in[2];     // [N] i32
    const float* rpm    = (const float*)d_in[3];   // [N] f32

    int* srcrow = (int*)d_ws;                      // N_TOK ints = 64 KB scratch

    rank_kernel<<<N_EXP, 1024, 0, stream>>>(routes, srcrow);
    combine_kernel<<<NBLK, THREADS, 0, stream>>>(
        (const float4*)hidden, (const float4*)eo, srcrow, rpm, (float4*)d_out);
}

// Round 13
// 73.948 us; speedup vs baseline: 1.0516x; 1.0290x over previous
//
#include <hip/hip_runtime.h>
#include <stdint.h>

// Problem dims (fixed by reference): E=16, B=8, S=2048, D=2048
#define N_TOK   16384          // B*S
#define D_MODEL 2048
#define N_EXP   16
#define CAP     1024           // N_TOK / N_EXP

#define BLK_TOK 8              // token rows per combine block
#define THREADS 256
#define STEPS   16             // float4 groups per thread
#define NBLK    (N_TOK / BLK_TOK)   // 2048 blocks = 8192 waves = 32/CU exactly

// keep  <=>  u < 0.9f  <=>  bits < 7549747<<9  (0.9f == 7549747*2^-23 exactly)
#define KEEP_THR_SH 0xE6666600u

// native 4-float vector for nontemporal builtin (HIP_vector_type is a class)
typedef float nfloat4 __attribute__((ext_vector_type(4)));

// ---------------------------------------------------------------------------
// rotl forced to a single v_alignbit_b32: rotl(x,r) == {x,x} >> (32-r).
// ---------------------------------------------------------------------------
template <int R>
__device__ __forceinline__ uint32_t rotl(uint32_t x) {
    uint32_t d;
    asm("v_alignbit_b32 %0, %1, %1, %2" : "=v"(d) : "v"(x), "n"(32 - R));
    return d;
}

// ---------------------------------------------------------------------------
// Threefry-2x32, 20 rounds, key = (0, 42) == jax.random.key(42).
// Partitionable path: counter = (0, i); 32-bit draw = XOR-fold x0 ^ x1.
// ---------------------------------------------------------------------------
__device__ __forceinline__ uint32_t tf_bits(uint32_t i) {
    const uint32_t k0 = 0u;
    const uint32_t k1 = 42u;
    const uint32_t k2 = 0x1BD11BDAu ^ 0u ^ 42u;
    uint32_t x0 = 0u + k0;        // counter hi = 0
    uint32_t x1 = i + k1;         // counter lo = i
#define TF_R(r) { x0 += x1; x1 = rotl<r>(x1) ^ x0; }
    TF_R(13) TF_R(15) TF_R(26) TF_R(6)
    x0 += k1; x1 += k2 + 1u;
    TF_R(17) TF_R(29) TF_R(16) TF_R(24)
    x0 += k2; x1 += k0 + 2u;
    TF_R(13) TF_R(15) TF_R(26) TF_R(6)
    x0 += k0; x1 += k1 + 3u;
    TF_R(17) TF_R(29) TF_R(16) TF_R(24)
    x0 += k1; x1 += k2 + 4u;
    TF_R(13) TF_R(15) TF_R(26) TF_R(6)
    x0 += k2; x1 += k0 + 5u;
#undef TF_R
    return x0 ^ x1;               // XOR-fold (partitionable sub-64 narrowing)
}

// ---------------------------------------------------------------------------
// Kernel 1: within-expert rank, two-level scan, single pass over routes.
// 16 blocks (one per expert) x 1024 threads (16 waves).
// srcrow[t] = routes[t]*CAP + rank(t).
// ---------------------------------------------------------------------------
__global__ __launch_bounds__(1024) void rank_kernel(const int* __restrict__ routes,
                                                    int* __restrict__ srcrow) {
    const int e    = blockIdx.x;
    const int tid  = threadIdx.x;       // 0..1023
    const int wave = tid >> 6;          // 0..15
    const int lane = tid & 63;
    __shared__ int wave_tot[16];

    const int4* r4 = (const int4*)routes;
    int4 rv[4];
    int  mycnt = 0;
    #pragma unroll
    for (int q = 0; q < 4; ++q) {
        rv[q] = r4[(wave << 8) + (lane << 2) + q];   // 16 consecutive tokens/lane
        mycnt += (rv[q].x == e) + (rv[q].y == e) + (rv[q].z == e) + (rv[q].w == e);
    }

    // inclusive wave scan of mycnt over lanes
    int pre = mycnt;
    #pragma unroll
    for (int d = 1; d < 64; d <<= 1) {
        int up = __shfl_up(pre, d);
        if (lane >= d) pre += up;
    }
    if (lane == 63) wave_tot[wave] = pre;
    __syncthreads();

    int wbase = 0;
    #pragma unroll
    for (int w = 0; w < 16; ++w) wbase += (w < wave) ? wave_tot[w] : 0;

    int p = e * CAP + wbase + (pre - mycnt);   // rank of lane's first match
    #pragma unroll
    for (int q = 0; q < 4; ++q) {
        const int tok = (((wave << 8) + (lane << 2) + q) << 2);
        if (rv[q].x == e) srcrow[tok + 0] = p++;
        if (rv[q].y == e) srcrow[tok + 1] = p++;
        if (rv[q].z == e) srcrow[tok + 2] = p++;
        if (rv[q].w == e) srcrow[tok + 3] = p++;
    }
}

// ---------------------------------------------------------------------------
// Kernel 2: combine + dropout + residual. Long-lived blocks (16 steps),
// 1-deep prefetch pinned with sched_barrier, <=64 VGPR (8 waves/SIMD),
// non-temporal stores for the never-re-read output.  (R9 best config.)
// ---------------------------------------------------------------------------
__global__ __launch_bounds__(THREADS, 8) void combine_kernel(
        const float4* __restrict__ hidden,
        const float4* __restrict__ eo4,
        const int*    __restrict__ srcrow,
        const float*  __restrict__ rpm,
        float4*       __restrict__ out) {
    const int b     = blockIdx.x;
    const int tid   = threadIdx.x;                 // 0..255
    const int t0    = b * BLK_TOK;
    const int gbase = b * (BLK_TOK * 512);         // first float4 of block

    // Block-uniform per-row scalars (scalarize to SGPRs), paid once per block
    int   r[BLK_TOK];
    float sc[BLK_TOK];
    #pragma unroll
    for (int q = 0; q < BLK_TOK; ++q) {
        r[q]  = srcrow[t0 + q];
        sc[q] = rpm[t0 + q] * (1.0f / 0.9f);
    }

    // 1-deep pipeline: loads for step k+1 issue before threefry of step k.
    float4 h = hidden[gbase + tid];
    float4 e = eo4[(r[0] << 9) + tid];

    #pragma unroll
    for (int k = 0; k < STEPS; ++k) {
        float4 hn, en;
        if (k + 1 < STEPS) {
            const int idx = (k + 1) * THREADS + tid;       // within-block f4 idx
            hn = hidden[gbase + idx];
            en = eo4[(r[(k + 1) >> 1] << 9) + (idx & 511)];
        }
        // pin: next-step loads may not sink below; threefry may not hoist above
        __builtin_amdgcn_sched_barrier(0);

        const uint32_t j = (uint32_t)(gbase + k * THREADS + tid) << 2;
        const uint32_t b0 = tf_bits(j + 0);
        const uint32_t b1 = tf_bits(j + 1);
        const uint32_t b2 = tf_bits(j + 2);
        const uint32_t b3 = tf_bits(j + 3);

        const float s  = sc[k >> 1];
        const float m0 = (b0 < KEEP_THR_SH) ? s : 0.0f;
        const float m1 = (b1 < KEEP_THR_SH) ? s : 0.0f;
        const float m2 = (b2 < KEEP_THR_SH) ? s : 0.0f;
        const float m3 = (b3 < KEEP_THR_SH) ? s : 0.0f;

        nfloat4 o;
        o.x = fmaf(m0, e.x, h.x);
        o.y = fmaf(m1, e.y, h.y);
        o.z = fmaf(m2, e.z, h.z);
        o.w = fmaf(m3, e.w, h.w);
        __builtin_nontemporal_store(o, (nfloat4*)&out[gbase + k * THREADS + tid]);

        if (k + 1 < STEPS) { h = hn; e = en; }
    }
}

// ---------------------------------------------------------------------------
extern "C" void kernel_launch(void* const* d_in, const int* in_sizes, int n_in,
                              void* d_out, int out_size, void* d_ws, size_t ws_size,
                              hipStream_t stream) {
    const float* hidden = (const float*)d_in[0];   // [B,S,D] f32
    const float* eo     = (const float*)d_in[1];   // [E,CAP,D] f32
    const int*   routes = (const int*)d_in[2];     // [N] i32
    const float* rpm    = (const float*)d_in[3];   // [N] f32

    int* srcrow = (int*)d_ws;                      // N_TOK ints = 64 KB scratch

    rank_kernel<<<N_EXP, 1024, 0, stream>>>(routes, srcrow);
    combine_kernel<<<NBLK, THREADS, 0, stream>>>(
        (const float4*)hidden, (const float4*)eo, srcrow, rpm, (float4*)d_out);
}